// Round 1
// baseline (7577.011 us; speedup 1.0000x reference)
//
#include <hip/hip_runtime.h>

#define BB 16
#define CC 256
#define NN 4096
#define MM 1024
#define EPSV 1e-5f
#define SCALE (1.0f/16.0f)   // 1/sqrt(C)

// ---- workspace layout (float offsets). Total 25,465,856 floats = ~102 MB ----
#define OFF_MU    0            // 4096
#define OFF_SCORE 4096         // 65536
#define OFF_IDX   69632        // 32768 ints (idx_s then idx_g)
#define OFF_U     102400       // 65536
#define OFF_WVZ   167936       // 65536
#define OFF_WF12  233472       // 65536
#define OFF_BVZ   299008       // 256
#define OFF_BZ    299264       // 256
#define OFF_K     299520       // 4194304
#define OFF_VZ    4493824      // 4194304
#define OFF_Z     8688128      // 16777216
#define OFF_BN    25465344     // 512

__global__ __launch_bounds__(256) void zero_bn_kernel(float* bn) {
    int t = threadIdx.x;
    bn[t] = 0.f; bn[t + CC] = 0.f;
}

// mu[b,c] = mean over n of x[b,c,n]
__global__ __launch_bounds__(256) void mean_kernel(const float* __restrict__ x, float* __restrict__ mu) {
    int c = blockIdx.x, b = blockIdx.y, t = threadIdx.x;
    const float* p = x + ((size_t)b * CC + c) * NN;
    float s = 0.f;
    for (int n = t; n < NN; n += 256) s += p[n];
    __shared__ float red[256];
    red[t] = s; __syncthreads();
    for (int w = 128; w > 0; w >>= 1) { if (t < w) red[t] += red[t + w]; __syncthreads(); }
    if (t == 0) mu[b * CC + c] = red[0] * (1.0f / NN);
}

// score[b,n] = sum_c (x[b,c,n]-mu[b,c])^2
__global__ __launch_bounds__(256) void score_kernel(const float* __restrict__ x, const float* __restrict__ mu,
                                                    float* __restrict__ score) {
    int b = blockIdx.y, t = threadIdx.x;
    int n = blockIdx.x * 256 + t;
    __shared__ float smu[CC];
    smu[t] = mu[b * CC + t];
    __syncthreads();
    float acc = 0.f;
    const float* p = x + (size_t)b * CC * NN + n;
    for (int c = 0; c < CC; ++c) { float d = p[(size_t)c * NN] - smu[c]; acc += d * d; }
    score[b * NN + n] = acc;
}

// bitonic sort 4096 (score,idx) descending per batch; head 1024 -> idx_s, tail 1024 -> idx_g
__global__ __launch_bounds__(1024) void topk_kernel(const float* __restrict__ score,
                                                    int* __restrict__ idx_s, int* __restrict__ idx_g) {
    int b = blockIdx.x, t = threadIdx.x;
    __shared__ float v[NN];
    __shared__ int   id[NN];
    for (int q = t; q < NN; q += 1024) { v[q] = score[b * NN + q]; id[q] = q; }
    __syncthreads();
    for (int k = 2; k <= NN; k <<= 1) {
        for (int j = k >> 1; j > 0; j >>= 1) {
            for (int q = t; q < NN; q += 1024) {
                int ixj = q ^ j;
                if (ixj > q) {
                    float va = v[q], vb = v[ixj];
                    int ia = id[q], ib = id[ixj];
                    // "a ranks before b" in descending order (tie: lower index first)
                    bool before = (va > vb) || (va == vb && ia < ib);
                    bool descBlock = ((q & k) == 0);
                    bool doswap = descBlock ? (!before) : before;
                    if (doswap) { v[q] = vb; v[ixj] = va; id[q] = ib; id[ixj] = ia; }
                }
            }
            __syncthreads();
        }
    }
    if (t < MM) {
        idx_s[b * MM + t] = id[t];
        idx_g[b * MM + t] = id[NN - MM + t];
    }
}

// Cm[e,f] = sum_k A[e*lda+aoff+k] * Bm[k*CC+f]
__global__ __launch_bounds__(256) void smallmm_kernel(const float* __restrict__ A, int lda, int aoff,
                                                      const float* __restrict__ Bm, float* __restrict__ Cm) {
    int e = blockIdx.x, t = threadIdx.x;
    __shared__ float arow[CC];
    arow[t] = A[e * lda + aoff + t];
    __syncthreads();
    float acc = 0.f;
    for (int k = 0; k < CC; ++k) acc += arow[k] * Bm[k * CC + t];
    Cm[e * CC + t] = acc;
}

// bvz[e] = sum_d U[e,d]*bv[d]
__global__ __launch_bounds__(256) void bvz_kernel(const float* __restrict__ U, const float* __restrict__ bv,
                                                  float* __restrict__ bvz) {
    int e = threadIdx.x;
    float acc = 0.f;
    for (int d = 0; d < CC; ++d) acc += U[e * CC + d] * bv[d];
    bvz[e] = acc;
}

// bz[e] = bf[e] + Wf1[e,:]·bo_s + Wf2[e,:]·bo_g
__global__ __launch_bounds__(256) void bz_kernel(const float* __restrict__ Wf, const float* __restrict__ bf,
                                                 const float* __restrict__ bo_s, const float* __restrict__ bo_g,
                                                 float* __restrict__ bz) {
    int e = threadIdx.x;
    float acc = bf[e];
    for (int c = 0; c < CC; ++c)
        acc += Wf[e * 2 * CC + c] * bo_s[c] + Wf[e * 2 * CC + CC + c] * bo_g[c];
    bz[e] = acc;
}

__global__ __launch_bounds__(256) void wf12_kernel(const float* __restrict__ Wf, float* __restrict__ Wf12) {
    int e = blockIdx.x, c = threadIdx.x;
    Wf12[e * CC + c] = Wf[e * 2 * CC + c] + Wf[e * 2 * CC + CC + c];
}

// out[b,i,j] = sum_k W[j,k] * X[b,k,col(i)] + bias[j];  col(i)=gidx or i. 64x64 tile, 4x4/thread.
template<bool GATHER>
__global__ __launch_bounds__(256) void proj_gemm(const float* __restrict__ X, const float* __restrict__ W,
                                                 const float* __restrict__ bias, const int* __restrict__ gidx,
                                                 float* __restrict__ out, int NI) {
    int b = blockIdx.z;
    int i0 = blockIdx.x * 64, j0 = blockIdx.y * 64;
    int t = threadIdx.x, ti = t & 15, tj = t >> 4;
    __shared__ float Xs[16][68];
    __shared__ float Ws[16][68];
    __shared__ int cols[64];
    if (t < 64) cols[t] = GATHER ? gidx[b * NI + i0 + t] : (i0 + t);
    float acc[4][4] = {};
    const float* Xb = X + (size_t)b * CC * NN;
    int kk = t >> 4;          // 0..15 k-row for Xs load
    int il = t & 15;          // i lane
    int jj = t >> 2;          // 0..63 j-row for Ws load
    int kq = (t & 3) * 4;
    __syncthreads();
    for (int k0 = 0; k0 < CC; k0 += 16) {
        const float* xr = Xb + (size_t)(k0 + kk) * NN;
#pragma unroll
        for (int q = 0; q < 4; ++q) Xs[kk][il + q * 16] = xr[cols[il + q * 16]];
        float4 wv = *(const float4*)&W[(j0 + jj) * CC + k0 + kq];
        Ws[kq + 0][jj] = wv.x; Ws[kq + 1][jj] = wv.y; Ws[kq + 2][jj] = wv.z; Ws[kq + 3][jj] = wv.w;
        __syncthreads();
#pragma unroll
        for (int kx = 0; kx < 16; ++kx) {
            float4 a = *(const float4*)&Xs[kx][ti * 4];
            float4 bbv = *(const float4*)&Ws[kx][tj * 4];
            float av[4] = {a.x, a.y, a.z, a.w};
            float bv4[4] = {bbv.x, bbv.y, bbv.z, bbv.w};
#pragma unroll
            for (int r = 0; r < 4; ++r)
#pragma unroll
                for (int s2 = 0; s2 < 4; ++s2) acc[r][s2] += av[r] * bv4[s2];
        }
        __syncthreads();
    }
    float bv4[4];
#pragma unroll
    for (int s2 = 0; s2 < 4; ++s2) bv4[s2] = bias[j0 + tj * 4 + s2];
#pragma unroll
    for (int r = 0; r < 4; ++r) {
        float4 o;
        o.x = acc[r][0] + bv4[0]; o.y = acc[r][1] + bv4[1];
        o.z = acc[r][2] + bv4[2]; o.w = acc[r][3] + bv4[3];
        *(float4*)&out[((size_t)b * NI + i0 + ti * 4 + r) * CC + j0 + tj * 4] = o;
    }
}

// attention: per block 8 query rows, full M. S in LDS, softmax (no max-sub: |s|<~2), Z += P@Vz / l
#define TNA 8
__global__ __launch_bounds__(256) void attn_kernel(const float* __restrict__ Q,   // [B][N][C]
                                                   const float* __restrict__ Km,  // [B][M][C]
                                                   const float* __restrict__ Vz,  // [B][M][C]
                                                   float* __restrict__ Z) {       // [B][N][C] +=
    int b = blockIdx.y, n0 = blockIdx.x * TNA, t = threadIdx.x;
    __shared__ float Qs[TNA][260];
    __shared__ float P[TNA][MM];
    __shared__ float lrow[TNA];
    {
        int r = t >> 5, c0 = (t & 31) * 8;
        const float* q = Q + ((size_t)b * NN + n0 + r) * CC + c0;
        float4 q0 = *(const float4*)q, q1 = *(const float4*)(q + 4);
        *(float4*)&Qs[r][c0] = q0; *(float4*)&Qs[r][c0 + 4] = q1;
    }
    if (t < TNA) lrow[t] = 0.f;
    __syncthreads();
    // phase 1: scores for m = 4t..4t+3 against all 8 rows
    float accs[TNA][4];
#pragma unroll
    for (int i = 0; i < TNA; ++i)
#pragma unroll
        for (int r = 0; r < 4; ++r) accs[i][r] = 0.f;
    {
        int m0 = t * 4;
        const float* kb = Km + ((size_t)b * MM + m0) * CC;
        for (int k = 0; k < CC; k += 4) {
            float4 kv0 = *(const float4*)(kb + 0 * CC + k);
            float4 kv1 = *(const float4*)(kb + 1 * CC + k);
            float4 kv2 = *(const float4*)(kb + 2 * CC + k);
            float4 kv3 = *(const float4*)(kb + 3 * CC + k);
#pragma unroll
            for (int i = 0; i < TNA; ++i) {
                float4 qv = *(const float4*)&Qs[i][k];
                accs[i][0] += qv.x * kv0.x + qv.y * kv0.y + qv.z * kv0.z + qv.w * kv0.w;
                accs[i][1] += qv.x * kv1.x + qv.y * kv1.y + qv.z * kv1.z + qv.w * kv1.w;
                accs[i][2] += qv.x * kv2.x + qv.y * kv2.y + qv.z * kv2.z + qv.w * kv2.w;
                accs[i][3] += qv.x * kv3.x + qv.y * kv3.y + qv.z * kv3.z + qv.w * kv3.w;
            }
        }
    }
    {
        int m0 = t * 4;
#pragma unroll
        for (int i = 0; i < TNA; ++i) {
            float4 pv;
            pv.x = __expf(accs[i][0] * SCALE);
            pv.y = __expf(accs[i][1] * SCALE);
            pv.z = __expf(accs[i][2] * SCALE);
            pv.w = __expf(accs[i][3] * SCALE);
            *(float4*)&P[i][m0] = pv;
            atomicAdd(&lrow[i], pv.x + pv.y + pv.z + pv.w);
        }
    }
    __syncthreads();
    // phase 2: Z[n0+i][e0..e0+7] += (P[i,:] @ Vz[:, e]) / l[i]
    int i = t >> 5, e0 = (t & 31) * 8;
    float4 a0 = {0, 0, 0, 0}, a1 = {0, 0, 0, 0};
    const float* vzb = Vz + (size_t)b * MM * CC + e0;
    for (int m = 0; m < MM; ++m) {
        float p = P[i][m];
        float4 v0 = *(const float4*)(vzb + (size_t)m * CC);
        float4 v1 = *(const float4*)(vzb + (size_t)m * CC + 4);
        a0.x += p * v0.x; a0.y += p * v0.y; a0.z += p * v0.z; a0.w += p * v0.w;
        a1.x += p * v1.x; a1.y += p * v1.y; a1.z += p * v1.z; a1.w += p * v1.w;
    }
    float inv = 1.0f / lrow[i];
    float* zp = Z + ((size_t)b * NN + n0 + i) * CC + e0;
    float4 z0 = *(const float4*)zp, z1 = *(const float4*)(zp + 4);
    z0.x += a0.x * inv; z0.y += a0.y * inv; z0.z += a0.z * inv; z0.w += a0.w * inv;
    z1.x += a1.x * inv; z1.y += a1.y * inv; z1.z += a1.z * inv; z1.w += a1.w * inv;
    *(float4*)zp = z0; *(float4*)(zp + 4) = z1;
}

// BN stats: per-channel sum and sumsq over B*N rows of Z [B*N][C]
__global__ __launch_bounds__(256) void bn_stats_kernel(const float* __restrict__ Z, float* __restrict__ bn) {
    int blk = blockIdx.x, e = threadIdx.x;
    const float* p = Z + (size_t)blk * 256 * CC + e;
    float s1 = 0.f, s2 = 0.f;
    for (int r = 0; r < 256; ++r) { float v = p[(size_t)r * CC]; s1 += v; s2 += v * v; }
    atomicAdd(&bn[e], s1);
    atomicAdd(&bn[CC + e], s2);
}

// normalize + relu + transpose [B][N][C] -> [B][C][N]
__global__ __launch_bounds__(256) void bn_apply_kernel(const float* __restrict__ Z, const float* __restrict__ bn,
                                                       const float* __restrict__ gamma, const float* __restrict__ beta,
                                                       float* __restrict__ out) {
    int b = blockIdx.z, e0 = blockIdx.y * 32, n0 = blockIdx.x * 32, t = threadIdx.x;
    __shared__ float tile[32][33];
    int c = t & 31, r0 = (t >> 5) * 4;
#pragma unroll
    for (int q = 0; q < 4; ++q)
        tile[r0 + q][c] = Z[((size_t)b * NN + n0 + r0 + q) * CC + e0 + c];
    __syncthreads();
    int n = t & 31, er0 = (t >> 5) * 4;
    const float invcnt = 1.0f / (BB * NN);
#pragma unroll
    for (int q = 0; q < 4; ++q) {
        int e = e0 + er0 + q;
        float mean = bn[e] * invcnt;
        float var = bn[CC + e] * invcnt - mean * mean;
        float rs = rsqrtf(var + EPSV);
        float v = (tile[n][er0 + q] - mean) * rs * gamma[e] + beta[e];
        out[((size_t)b * CC + e) * NN + n0 + n] = fmaxf(v, 0.f);
    }
}

extern "C" void kernel_launch(void* const* d_in, const int* in_sizes, int n_in,
                              void* d_out, int out_size, void* d_ws, size_t ws_size,
                              hipStream_t stream) {
    const float* x    = (const float*)d_in[0];
    // d_in[1] = num_select (compile-time MM)
    const float* Wq_s = (const float*)d_in[2];  const float* bq_s = (const float*)d_in[3];
    const float* Wk_s = (const float*)d_in[4];  const float* bk_s = (const float*)d_in[5];
    const float* Wv_s = (const float*)d_in[6];  const float* bv_s = (const float*)d_in[7];
    const float* Wo_s = (const float*)d_in[8];  const float* bo_s = (const float*)d_in[9];
    const float* Wq_g = (const float*)d_in[10]; const float* bq_g = (const float*)d_in[11];
    const float* Wk_g = (const float*)d_in[12]; const float* bk_g = (const float*)d_in[13];
    const float* Wv_g = (const float*)d_in[14]; const float* bv_g = (const float*)d_in[15];
    const float* Wo_g = (const float*)d_in[16]; const float* bo_g = (const float*)d_in[17];
    const float* Wf   = (const float*)d_in[18]; const float* bf   = (const float*)d_in[19];
    const float* gamma = (const float*)d_in[20]; const float* beta = (const float*)d_in[21];

    float* ws    = (float*)d_ws;               // needs ~102 MB
    float* mu    = ws + OFF_MU;
    float* score = ws + OFF_SCORE;
    int*   idx_s = (int*)(ws + OFF_IDX);
    int*   idx_g = idx_s + BB * MM;
    float* U     = ws + OFF_U;
    float* Wvz   = ws + OFF_WVZ;
    float* Wf12  = ws + OFF_WF12;
    float* bvz   = ws + OFF_BVZ;
    float* bz    = ws + OFF_BZ;
    float* Kbuf  = ws + OFF_K;
    float* Vzbuf = ws + OFF_VZ;
    float* Z     = ws + OFF_Z;
    float* bn    = ws + OFF_BN;
    float* Q     = (float*)d_out;              // d_out doubles as Q scratch

    zero_bn_kernel<<<1, 256, 0, stream>>>(bn);
    mean_kernel<<<dim3(CC, BB), 256, 0, stream>>>(x, mu);
    score_kernel<<<dim3(NN / 256, BB), 256, 0, stream>>>(x, mu, score);
    topk_kernel<<<BB, 1024, 0, stream>>>(score, idx_s, idx_g);
    wf12_kernel<<<CC, 256, 0, stream>>>(Wf, Wf12);
    bz_kernel<<<1, 256, 0, stream>>>(Wf, bf, bo_s, bo_g, bz);
    // Z = Wf12 @ x + bz   (residual x through both conv halves)
    proj_gemm<false><<<dim3(NN / 64, 4, BB), 256, 0, stream>>>(x, Wf12, bz, nullptr, Z, NN);

    for (int br = 0; br < 2; ++br) {
        const float* Wo = br ? Wo_g : Wo_s;  const float* bo = br ? bo_g : bo_s;
        const float* Wv = br ? Wv_g : Wv_s;  const float* bv = br ? bv_g : bv_s;
        const float* Wk = br ? Wk_g : Wk_s;  const float* bk = br ? bk_g : bk_s;
        const float* Wq = br ? Wq_g : Wq_s;  const float* bq = br ? bq_g : bq_s;
        int* idx = br ? idx_g : idx_s;
        int aoff = br ? CC : 0;
        // U = Wf_half @ Wo ; Wvz = U @ Wv ; bvz = U @ bv
        smallmm_kernel<<<CC, 256, 0, stream>>>(Wf, 2 * CC, aoff, Wo, U);
        smallmm_kernel<<<CC, 256, 0, stream>>>(U, CC, 0, Wv, Wvz);
        bvz_kernel<<<1, 256, 0, stream>>>(U, bv, bvz);
        // K and Vz projections of gathered context
        proj_gemm<true><<<dim3(MM / 64, 4, BB), 256, 0, stream>>>(x, Wk, bk, idx, Kbuf, MM);
        proj_gemm<true><<<dim3(MM / 64, 4, BB), 256, 0, stream>>>(x, Wvz, bvz, idx, Vzbuf, MM);
        // Q projection (into d_out scratch)
        proj_gemm<false><<<dim3(NN / 64, 4, BB), 256, 0, stream>>>(x, Wq, bq, nullptr, Q, NN);
        // Z += softmax(QK^T/16) @ Vz
        attn_kernel<<<dim3(NN / TNA, BB), 256, 0, stream>>>(Q, Kbuf, Vzbuf, Z);
    }

    bn_stats_kernel<<<BB * NN / 256, 256, 0, stream>>>(Z, bn);
    bn_apply_kernel<<<dim3(NN / 32, CC / 32, BB), 256, 0, stream>>>(Z, bn, gamma, beta, (float*)d_out);
}

// Round 2
// 1559.594 us; speedup vs baseline: 4.8583x; 4.8583x over previous
//
#include <hip/hip_runtime.h>

#define BB 16
#define CC 256
#define NN 4096
#define MM 1024
#define EPSV 1e-5f
#define SCALE (1.0f/16.0f)   // 1/sqrt(C)

// ---- workspace layout (float offsets) ----
#define OFF_MU    0            // 4096
#define OFF_SCORE 4096         // 65536
#define OFF_IDX   69632        // 32768 ints (idx_s then idx_g)
#define OFF_U     102400       // 65536
#define OFF_WVZ   167936       // 65536
#define OFF_WF12  233472       // 65536
#define OFF_BVZ   299008       // 256
#define OFF_BZ    299264       // 256
#define OFF_K     299520       // K bf16 [B][M][C] (uses 2.1M floats of space)
#define OFF_VZ    4493824      // Vt bf16 [B][C][M]
#define OFF_Z     8688128      // 16777216
#define OFF_BN    25465344     // 512

typedef __attribute__((ext_vector_type(8))) short s16x8;
typedef __attribute__((ext_vector_type(4))) float f32x4;

__device__ __forceinline__ unsigned short f2bf(float f) {
    unsigned int u = __float_as_uint(f);
    return (unsigned short)((u + 0x7FFFu + ((u >> 16) & 1u)) >> 16);
}
__device__ __forceinline__ float bf2f(unsigned short h) {
    return __uint_as_float(((unsigned int)h) << 16);
}

__global__ __launch_bounds__(256) void zero_bn_kernel(float* bn) {
    int t = threadIdx.x;
    bn[t] = 0.f; bn[t + CC] = 0.f;
}

// mu[b,c] = mean over n of x[b,c,n]
__global__ __launch_bounds__(256) void mean_kernel(const float* __restrict__ x, float* __restrict__ mu) {
    int c = blockIdx.x, b = blockIdx.y, t = threadIdx.x;
    const float* p = x + ((size_t)b * CC + c) * NN;
    float s = 0.f;
    for (int n = t; n < NN; n += 256) s += p[n];
    __shared__ float red[256];
    red[t] = s; __syncthreads();
    for (int w = 128; w > 0; w >>= 1) { if (t < w) red[t] += red[t + w]; __syncthreads(); }
    if (t == 0) mu[b * CC + c] = red[0] * (1.0f / NN);
}

// score[b,n] = sum_c (x[b,c,n]-mu[b,c])^2
__global__ __launch_bounds__(256) void score_kernel(const float* __restrict__ x, const float* __restrict__ mu,
                                                    float* __restrict__ score) {
    int b = blockIdx.y, t = threadIdx.x;
    int n = blockIdx.x * 256 + t;
    __shared__ float smu[CC];
    smu[t] = mu[b * CC + t];
    __syncthreads();
    float acc = 0.f;
    const float* p = x + (size_t)b * CC * NN + n;
    for (int c = 0; c < CC; ++c) { float d = p[(size_t)c * NN] - smu[c]; acc += d * d; }
    score[b * NN + n] = acc;
}

// bitonic sort 4096 (score,idx) descending per batch; head 1024 -> idx_s, tail 1024 -> idx_g
__global__ __launch_bounds__(1024) void topk_kernel(const float* __restrict__ score,
                                                    int* __restrict__ idx_s, int* __restrict__ idx_g) {
    int b = blockIdx.x, t = threadIdx.x;
    __shared__ float v[NN];
    __shared__ int   id[NN];
    for (int q = t; q < NN; q += 1024) { v[q] = score[b * NN + q]; id[q] = q; }
    __syncthreads();
    for (int k = 2; k <= NN; k <<= 1) {
        for (int j = k >> 1; j > 0; j >>= 1) {
            for (int q = t; q < NN; q += 1024) {
                int ixj = q ^ j;
                if (ixj > q) {
                    float va = v[q], vb = v[ixj];
                    int ia = id[q], ib = id[ixj];
                    bool before = (va > vb) || (va == vb && ia < ib);
                    bool descBlock = ((q & k) == 0);
                    bool doswap = descBlock ? (!before) : before;
                    if (doswap) { v[q] = vb; v[ixj] = va; id[q] = ib; id[ixj] = ia; }
                }
            }
            __syncthreads();
        }
    }
    if (t < MM) {
        idx_s[b * MM + t] = id[t];
        idx_g[b * MM + t] = id[NN - MM + t];
    }
}

// Cm[e,f] = sum_k A[e*lda+aoff+k] * Bm[k*CC+f]
__global__ __launch_bounds__(256) void smallmm_kernel(const float* __restrict__ A, int lda, int aoff,
                                                      const float* __restrict__ Bm, float* __restrict__ Cm) {
    int e = blockIdx.x, t = threadIdx.x;
    __shared__ float arow[CC];
    arow[t] = A[e * lda + aoff + t];
    __syncthreads();
    float acc = 0.f;
    for (int k = 0; k < CC; ++k) acc += arow[k] * Bm[k * CC + t];
    Cm[e * CC + t] = acc;
}

__global__ __launch_bounds__(256) void bvz_kernel(const float* __restrict__ U, const float* __restrict__ bv,
                                                  float* __restrict__ bvz) {
    int e = threadIdx.x;
    float acc = 0.f;
    for (int d = 0; d < CC; ++d) acc += U[e * CC + d] * bv[d];
    bvz[e] = acc;
}

__global__ __launch_bounds__(256) void bz_kernel(const float* __restrict__ Wf, const float* __restrict__ bf,
                                                 const float* __restrict__ bo_s, const float* __restrict__ bo_g,
                                                 float* __restrict__ bz) {
    int e = threadIdx.x;
    float acc = bf[e];
    for (int c = 0; c < CC; ++c)
        acc += Wf[e * 2 * CC + c] * bo_s[c] + Wf[e * 2 * CC + CC + c] * bo_g[c];
    bz[e] = acc;
}

__global__ __launch_bounds__(256) void wf12_kernel(const float* __restrict__ Wf, float* __restrict__ Wf12) {
    int e = blockIdx.x, c = threadIdx.x;
    Wf12[e * CC + c] = Wf[e * 2 * CC + c] + Wf[e * 2 * CC + CC + c];
}

// out[b,i,j] = sum_k W[j,k] * X[b,k,col(i)] + bias[j];  col(i)=gidx or i. 64x64 tile, 4x4/thread.
// OMODE 0: fp32 [i][j]; 1: bf16 [i][j]; 2: bf16 transposed [j][i] (leading dim MM)
template<bool GATHER, int OMODE>
__global__ __launch_bounds__(256) void proj_gemm(const float* __restrict__ X, const float* __restrict__ W,
                                                 const float* __restrict__ bias, const int* __restrict__ gidx,
                                                 void* __restrict__ outp, int NI) {
    int b = blockIdx.z;
    int i0 = blockIdx.x * 64, j0 = blockIdx.y * 64;
    int t = threadIdx.x, ti = t & 15, tj = t >> 4;
    __shared__ float Xs[16][68];
    __shared__ float Ws[16][68];
    __shared__ int cols[64];
    if (t < 64) cols[t] = GATHER ? gidx[b * NI + i0 + t] : (i0 + t);
    float acc[4][4] = {};
    const float* Xb = X + (size_t)b * CC * NN;
    int kk = t >> 4;
    int il = t & 15;
    int jj = t >> 2;
    int kq = (t & 3) * 4;
    __syncthreads();
    for (int k0 = 0; k0 < CC; k0 += 16) {
        const float* xr = Xb + (size_t)(k0 + kk) * NN;
#pragma unroll
        for (int q = 0; q < 4; ++q) Xs[kk][il + q * 16] = xr[cols[il + q * 16]];
        float4 wv = *(const float4*)&W[(j0 + jj) * CC + k0 + kq];
        Ws[kq + 0][jj] = wv.x; Ws[kq + 1][jj] = wv.y; Ws[kq + 2][jj] = wv.z; Ws[kq + 3][jj] = wv.w;
        __syncthreads();
#pragma unroll
        for (int kx = 0; kx < 16; ++kx) {
            float4 a = *(const float4*)&Xs[kx][ti * 4];
            float4 bbv = *(const float4*)&Ws[kx][tj * 4];
            float av[4] = {a.x, a.y, a.z, a.w};
            float bv4[4] = {bbv.x, bbv.y, bbv.z, bbv.w};
#pragma unroll
            for (int r = 0; r < 4; ++r)
#pragma unroll
                for (int s2 = 0; s2 < 4; ++s2) acc[r][s2] += av[r] * bv4[s2];
        }
        __syncthreads();
    }
    float bv4[4];
#pragma unroll
    for (int s2 = 0; s2 < 4; ++s2) bv4[s2] = bias[j0 + tj * 4 + s2];
#pragma unroll
    for (int r = 0; r < 4; ++r)
#pragma unroll
        for (int s2 = 0; s2 < 4; ++s2) acc[r][s2] += bv4[s2];

    if (OMODE == 0) {
        float* ob = (float*)outp;
#pragma unroll
        for (int r = 0; r < 4; ++r) {
            float4 o;
            o.x = acc[r][0]; o.y = acc[r][1]; o.z = acc[r][2]; o.w = acc[r][3];
            *(float4*)&ob[((size_t)b * NI + i0 + ti * 4 + r) * CC + j0 + tj * 4] = o;
        }
    } else if (OMODE == 1) {
        unsigned short* ob = (unsigned short*)outp;
#pragma unroll
        for (int r = 0; r < 4; ++r) {
            uint2 pk;
            pk.x = (unsigned int)f2bf(acc[r][0]) | ((unsigned int)f2bf(acc[r][1]) << 16);
            pk.y = (unsigned int)f2bf(acc[r][2]) | ((unsigned int)f2bf(acc[r][3]) << 16);
            *(uint2*)&ob[((size_t)b * NI + i0 + ti * 4 + r) * CC + j0 + tj * 4] = pk;
        }
    } else {
        unsigned short* ob = (unsigned short*)outp;
#pragma unroll
        for (int s2 = 0; s2 < 4; ++s2) {
            uint2 pk;
            pk.x = (unsigned int)f2bf(acc[0][s2]) | ((unsigned int)f2bf(acc[1][s2]) << 16);
            pk.y = (unsigned int)f2bf(acc[2][s2]) | ((unsigned int)f2bf(acc[3][s2]) << 16);
            *(uint2*)&ob[((size_t)b * CC + j0 + tj * 4 + s2) * MM + i0 + ti * 4] = pk;
        }
    }
}

// ---- MFMA flash attention: 64 Q-rows/block, M-steps of 64, bf16 in / fp32 acc ----
#define TQ 64
#define TM 64
__global__ __launch_bounds__(256, 2) void attn_mfma_kernel(
    const unsigned short* __restrict__ Qg,   // [B][N][C] bf16
    const unsigned short* __restrict__ Kg,   // [B][M][C] bf16
    const unsigned short* __restrict__ Vtg,  // [B][C][M] bf16 (transposed)
    float* __restrict__ Z)                   // [B][N][C] +=
{
    __shared__ __align__(16) short Ks[TM][264];   // +8 pad: 2-way max bank aliasing
    __shared__ __align__(16) short Vs[CC][72];
    __shared__ __align__(16) short Ps[TQ][72];

    int b = blockIdx.y, n0 = blockIdx.x * TQ, t = threadIdx.x;
    int w = t >> 6, l = t & 63, g = l >> 4, c16 = l & 15;

    // Q fragments held in registers for the whole M loop (A-layout: row=lane&15, k=(lane>>4)*8+j)
    s16x8 qf[8];
    const unsigned short* qp = Qg + ((size_t)(b * NN + n0 + w * 16 + c16)) * CC + g * 8;
#pragma unroll
    for (int k8 = 0; k8 < 8; ++k8)
        qf[k8] = *(const s16x8*)(qp + k8 * 32);

    f32x4 O[16];
#pragma unroll
    for (int eg = 0; eg < 16; ++eg) O[eg] = (f32x4){0.f, 0.f, 0.f, 0.f};
    float rsum[4] = {0.f, 0.f, 0.f, 0.f};

    const unsigned short* Kb = Kg + (size_t)b * MM * CC;
    const unsigned short* Vb = Vtg + (size_t)b * CC * MM;

    for (int ms = 0; ms < 16; ++ms) {
        int m0 = ms * TM;
        // stage K tile [64][256] — source is contiguous 32 KB
        const unsigned short* kt = Kb + (size_t)m0 * CC;
#pragma unroll
        for (int it = 0; it < 8; ++it) {
            int id = it * 256 + t;
            int row = id >> 5, col = id & 31;
            *(uint4*)&Ks[row][col * 8] = *(const uint4*)(kt + row * CC + col * 8);
        }
        // stage Vt tile [256 e][64 m]
#pragma unroll
        for (int it = 0; it < 8; ++it) {
            int id = it * 256 + t;
            int e = id >> 3, cm = id & 7;
            *(uint4*)&Vs[e][cm * 8] = *(const uint4*)(Vb + (size_t)e * MM + m0 + cm * 8);
        }
        __syncthreads();

        // S = Q K^T : wave w owns Q rows [w*16, w*16+16), 4 m-groups of 16
        f32x4 S4[4];
#pragma unroll
        for (int mg = 0; mg < 4; ++mg) S4[mg] = (f32x4){0.f, 0.f, 0.f, 0.f};
#pragma unroll
        for (int mg = 0; mg < 4; ++mg) {
            const short* kr = &Ks[mg * 16 + c16][g * 8];
#pragma unroll
            for (int k8 = 0; k8 < 8; ++k8)
                S4[mg] = __builtin_amdgcn_mfma_f32_16x16x32_bf16(
                    qf[k8], *(const s16x8*)(kr + k8 * 32), S4[mg], 0, 0, 0);
        }
        // exp (no max-sub: |s|<~3), bf16-round, row-sum over cols, write P to LDS in A-layout source
#pragma unroll
        for (int mg = 0; mg < 4; ++mg) {
#pragma unroll
            for (int r = 0; r < 4; ++r) {
                float e = __expf(S4[mg][r] * SCALE);
                unsigned short h = f2bf(e);
                Ps[w * 16 + g * 4 + r][mg * 16 + c16] = (short)h;
                float v = bf2f(h);   // sum the bf16-rounded values for exact consistency with PV
                v += __shfl_xor(v, 1);
                v += __shfl_xor(v, 2);
                v += __shfl_xor(v, 4);
                v += __shfl_xor(v, 8);
                rsum[r] += v;
            }
        }
        __syncthreads();

        // O += P V  (A from Ps, B from Vs)
#pragma unroll
        for (int mk = 0; mk < 2; ++mk) {
            s16x8 pf = *(const s16x8*)&Ps[w * 16 + c16][mk * 32 + g * 8];
#pragma unroll
            for (int eg = 0; eg < 16; ++eg) {
                s16x8 vf = *(const s16x8*)&Vs[eg * 16 + c16][mk * 32 + g * 8];
                O[eg] = __builtin_amdgcn_mfma_f32_16x16x32_bf16(pf, vf, O[eg], 0, 0, 0);
            }
        }
        __syncthreads();   // protect Ks/Vs restage next iter
    }

    // normalize rows by rsum and accumulate into Z (C/D layout: row=g*4+r matches rsum[r])
    float inv[4];
#pragma unroll
    for (int r = 0; r < 4; ++r) inv[r] = 1.0f / rsum[r];
    float* zb = Z + ((size_t)(b * NN + n0 + w * 16 + g * 4)) * CC + c16;
#pragma unroll
    for (int eg = 0; eg < 16; ++eg) {
#pragma unroll
        for (int r = 0; r < 4; ++r) {
            float* zp = zb + (size_t)r * CC + eg * 16;
            *zp += O[eg][r] * inv[r];
        }
    }
}

// BN stats: per-channel sum and sumsq over B*N rows of Z [B*N][C]
__global__ __launch_bounds__(256) void bn_stats_kernel(const float* __restrict__ Z, float* __restrict__ bn) {
    int blk = blockIdx.x, e = threadIdx.x;
    const float* p = Z + (size_t)blk * 256 * CC + e;
    float s1 = 0.f, s2 = 0.f;
    for (int r = 0; r < 256; ++r) { float v = p[(size_t)r * CC]; s1 += v; s2 += v * v; }
    atomicAdd(&bn[e], s1);
    atomicAdd(&bn[CC + e], s2);
}

// normalize + relu + transpose [B][N][C] -> [B][C][N]
__global__ __launch_bounds__(256) void bn_apply_kernel(const float* __restrict__ Z, const float* __restrict__ bn,
                                                       const float* __restrict__ gamma, const float* __restrict__ beta,
                                                       float* __restrict__ out) {
    int b = blockIdx.z, e0 = blockIdx.y * 32, n0 = blockIdx.x * 32, t = threadIdx.x;
    __shared__ float tile[32][33];
    int c = t & 31, r0 = (t >> 5) * 4;
#pragma unroll
    for (int q = 0; q < 4; ++q)
        tile[r0 + q][c] = Z[((size_t)b * NN + n0 + r0 + q) * CC + e0 + c];
    __syncthreads();
    int n = t & 31, er0 = (t >> 5) * 4;
    const float invcnt = 1.0f / (BB * NN);
#pragma unroll
    for (int q = 0; q < 4; ++q) {
        int e = e0 + er0 + q;
        float mean = bn[e] * invcnt;
        float var = bn[CC + e] * invcnt - mean * mean;
        float rs = rsqrtf(var + EPSV);
        float v = (tile[n][er0 + q] - mean) * rs * gamma[e] + beta[e];
        out[((size_t)b * CC + e) * NN + n0 + n] = fmaxf(v, 0.f);
    }
}

extern "C" void kernel_launch(void* const* d_in, const int* in_sizes, int n_in,
                              void* d_out, int out_size, void* d_ws, size_t ws_size,
                              hipStream_t stream) {
    const float* x    = (const float*)d_in[0];
    const float* Wq_s = (const float*)d_in[2];  const float* bq_s = (const float*)d_in[3];
    const float* Wk_s = (const float*)d_in[4];  const float* bk_s = (const float*)d_in[5];
    const float* Wv_s = (const float*)d_in[6];  const float* bv_s = (const float*)d_in[7];
    const float* Wo_s = (const float*)d_in[8];  const float* bo_s = (const float*)d_in[9];
    const float* Wq_g = (const float*)d_in[10]; const float* bq_g = (const float*)d_in[11];
    const float* Wk_g = (const float*)d_in[12]; const float* bk_g = (const float*)d_in[13];
    const float* Wv_g = (const float*)d_in[14]; const float* bv_g = (const float*)d_in[15];
    const float* Wo_g = (const float*)d_in[16]; const float* bo_g = (const float*)d_in[17];
    const float* Wf   = (const float*)d_in[18]; const float* bf   = (const float*)d_in[19];
    const float* gamma = (const float*)d_in[20]; const float* beta = (const float*)d_in[21];

    float* ws    = (float*)d_ws;
    float* mu    = ws + OFF_MU;
    float* score = ws + OFF_SCORE;
    int*   idx_s = (int*)(ws + OFF_IDX);
    int*   idx_g = idx_s + BB * MM;
    float* U     = ws + OFF_U;
    float* Wvz   = ws + OFF_WVZ;
    float* Wf12  = ws + OFF_WF12;
    float* bvz   = ws + OFF_BVZ;
    float* bz    = ws + OFF_BZ;
    unsigned short* K16  = (unsigned short*)(ws + OFF_K);
    unsigned short* Vt16 = (unsigned short*)(ws + OFF_VZ);
    float* Z     = ws + OFF_Z;
    float* bn    = ws + OFF_BN;
    unsigned short* Q16 = (unsigned short*)d_out;   // d_out doubles as Q scratch (33.5 MB of 64)

    zero_bn_kernel<<<1, 256, 0, stream>>>(bn);
    mean_kernel<<<dim3(CC, BB), 256, 0, stream>>>(x, mu);
    score_kernel<<<dim3(NN / 256, BB), 256, 0, stream>>>(x, mu, score);
    topk_kernel<<<BB, 1024, 0, stream>>>(score, idx_s, idx_g);
    wf12_kernel<<<CC, 256, 0, stream>>>(Wf, Wf12);
    bz_kernel<<<1, 256, 0, stream>>>(Wf, bf, bo_s, bo_g, bz);
    // Z = Wf12 @ x + bz   (residual x through both conv halves)
    proj_gemm<false, 0><<<dim3(NN / 64, 4, BB), 256, 0, stream>>>(x, Wf12, bz, nullptr, Z, NN);

    for (int br = 0; br < 2; ++br) {
        const float* Wo = br ? Wo_g : Wo_s;  const float* bo = br ? bo_g : bo_s;
        const float* Wv = br ? Wv_g : Wv_s;  const float* bv = br ? bv_g : bv_s;
        const float* Wk = br ? Wk_g : Wk_s;  const float* bk = br ? bk_g : bk_s;
        const float* Wq = br ? Wq_g : Wq_s;  const float* bq = br ? bq_g : bq_s;
        int* idx = br ? idx_g : idx_s;
        int aoff = br ? CC : 0;
        // U = Wf_half @ Wo ; Wvz = U @ Wv ; bvz = U @ bv
        smallmm_kernel<<<CC, 256, 0, stream>>>(Wf, 2 * CC, aoff, Wo, U);
        smallmm_kernel<<<CC, 256, 0, stream>>>(U, CC, 0, Wv, Wvz);
        bvz_kernel<<<1, 256, 0, stream>>>(U, bv, bvz);
        // K (bf16 row-major) and Vz (bf16 transposed [e][m]) projections of gathered context
        proj_gemm<true, 1><<<dim3(MM / 64, 4, BB), 256, 0, stream>>>(x, Wk, bk, idx, K16, MM);
        proj_gemm<true, 2><<<dim3(MM / 64, 4, BB), 256, 0, stream>>>(x, Wvz, bvz, idx, Vt16, MM);
        // Q projection bf16 (into d_out scratch)
        proj_gemm<false, 1><<<dim3(NN / 64, 4, BB), 256, 0, stream>>>(x, Wq, bq, nullptr, Q16, NN);
        // Z += softmax(QK^T/16) @ Vz   (MFMA)
        attn_mfma_kernel<<<dim3(NN / TQ, BB), 256, 0, stream>>>(Q16, K16, Vt16, Z);
    }

    bn_stats_kernel<<<BB * NN / 256, 256, 0, stream>>>(Z, bn);
    bn_apply_kernel<<<dim3(NN / 32, CC / 32, BB), 256, 0, stream>>>(Z, bn, gamma, beta, (float*)d_out);
}